// Round 2
// baseline (342.120 us; speedup 1.0000x reference)
//
#include <hip/hip_runtime.h>

#define NN 4096
#define NE 8192
#define NLG 32768
#define HCAP 131072
#define HMASK (HCAP - 1)

typedef unsigned int u32;

// ---------------- prep: fp32 copies (strided) + bias-sum3 ----------------
struct Seg { const float* src; float* dst; int n; int w; int ld; int type; };
struct SegPack { Seg s[12]; int cnt; };

__global__ __launch_bounds__(256) void prep_kernel(SegPack P) {
    int i0 = blockIdx.x * blockDim.x + threadIdx.x;
    int stride = gridDim.x * blockDim.x;
    for (int si = 0; si < P.cnt; ++si) {
        Seg sg = P.s[si];
        if (sg.type == 0) {
            for (int i = i0; i < sg.n; i += stride) {
                int r = i / sg.w, c = i - r * sg.w;
                sg.dst[(size_t)r * sg.ld + c] = sg.src[i];
            }
        } else {  // sum over K_HOP=3 rows of [3, n]
            for (int i = i0; i < sg.n; i += stride) {
                float a = 0.f;
#pragma unroll
                for (int k = 0; k < 3; ++k) a += sg.src[k * sg.n + i];
                sg.dst[i] = a;
            }
        }
    }
}

// ---------------- dedup: bitmask for A, hash (last-occurrence-wins) for Ll/Lu ----------------
__device__ __forceinline__ u32 ht_hash(u32 slot) { return (slot * 2654435761u) & HMASK; }

__device__ __forceinline__ void ht_insert(u32* keys, u32* vals, u32 slot, u32 eid) {
    u32 key = slot + 1u;
    u32 h = ht_hash(slot);
    for (;;) {
        u32 k = keys[h];
        if (k == key) { atomicMax(&vals[h], eid + 1u); return; }
        if (k == 0u) {
            u32 old = atomicCAS(&keys[h], 0u, key);
            if (old == 0u || old == key) { atomicMax(&vals[h], eid + 1u); return; }
            continue;  // bucket claimed by another key; re-check this bucket
        }
        h = (h + 1u) & HMASK;
    }
}

__device__ __forceinline__ u32 ht_find(const u32* keys, u32 slot) {
    u32 key = slot + 1u;
    u32 h = ht_hash(slot);
    for (;;) { if (keys[h] == key) return h; h = (h + 1u) & HMASK; }
}

__global__ __launch_bounds__(256) void scatter_prep(
    const int* nei, u32* Abits, u32* winA,
    const int* eil, u32* keysL, u32* valsL,
    const int* eiu, u32* keysU, u32* valsU)
{
    int id = blockIdx.x * blockDim.x + threadIdx.x;
    if (id < NE) {
        u32 u = (u32)nei[id], v = (u32)nei[NE + id];
        u32 slot = u * (u32)NN + v;
        u32 old = atomicOr(&Abits[slot >> 5], 1u << (slot & 31));
        winA[id] = ((old >> (slot & 31)) & 1u) ? 0u : 1u;
    } else if (id < NE + NLG) {
        int e = id - NE;
        u32 p = (u32)eil[e], q = (u32)eil[NLG + e];
        ht_insert(keysL, valsL, p * (u32)NE + q, (u32)e);
    } else if (id < NE + 2 * NLG) {
        int e = id - NE - NLG;
        u32 p = (u32)eiu[e], q = (u32)eiu[NLG + e];
        ht_insert(keysU, valsU, p * (u32)NE + q, (u32)e);
    }
}

__global__ __launch_bounds__(256) void winner_pass(
    const int* eil, const u32* keysL, const u32* valsL, u32* winL,
    const int* eiu, const u32* keysU, const u32* valsU, u32* winU)
{
    int id = blockIdx.x * blockDim.x + threadIdx.x;
    if (id < NLG) {
        u32 p = (u32)eil[id], q = (u32)eil[NLG + id];
        u32 h = ht_find(keysL, p * (u32)NE + q);
        winL[id] = (valsL[h] == (u32)id + 1u) ? 1u : 0u;
    } else if (id < 2 * NLG) {
        int e = id - NLG;
        u32 p = (u32)eiu[e], q = (u32)eiu[NLG + e];
        u32 h = ht_find(keysU, p * (u32)NE + q);
        winU[e] = (valsU[h] == (u32)e + 1u) ? 1u : 0u;
    }
}

// ---------------- SpMM: scatter-add over edge list, up to 3 fused segments ----------------
struct SpSeg { const int* idx; const float* attr; const u32* win; const float* src; float* dst;
               int nnz; int cols; int ld; int rowofs; };

__global__ __launch_bounds__(256) void spmm3(SpSeg a, SpSeg b, SpSeg c, int n0, int n1, int n2) {
    int id = blockIdx.x * blockDim.x + threadIdx.x;
    SpSeg s; int t;
    if (id < n0) { s = a; t = id; }
    else if (id < n0 + n1) { s = b; t = id - n0; }
    else if (id < n0 + n1 + n2) { s = c; t = id - n0 - n1; }
    else return;
    int e = t / s.cols, col = t - e * s.cols;
    if (!s.win[e]) return;
    int u = s.idx[e], v = s.idx[s.rowofs + e];
    float w = s.attr ? s.attr[e] : 1.0f;
    atomicAdd(&s.dst[(size_t)u * s.ld + col], w * s.src[(size_t)v * s.ld + col]);
}

// ---------------- fp32 tiled GEMM: C[M,N] = A[M,K] @ B[K,N] + bias, optional relu ----------------
// 64x64 tile, BK=16, 256 threads, 4x4 microtile. Optional second fp32 store.
__global__ __launch_bounds__(256) void gemm_kernel(
    const float* __restrict__ A, int lda,
    const float* __restrict__ B, int ldb,
    const float* __restrict__ bias,
    float* C, int ldc, float* C2,
    int M, int K, int relu)
{
    __shared__ float As[16][64];
    __shared__ float Bs[16][64];
    int tid = threadIdx.x;
    int bm = blockIdx.x * 64;
    int bn = blockIdx.y * 64;
    int aRow = tid >> 2;         // 0..63
    int aCol = (tid & 3) * 4;    // 0,4,8,12
    int bRow = tid >> 4;         // 0..15
    int bCol = (tid & 15) * 4;   // 0..60
    int ty = tid >> 4, tx = tid & 15;
    int m0 = ty * 4, n0 = tx * 4;
    float acc[4][4] = {};

    for (int k0 = 0; k0 < K; k0 += 16) {
        float4 av = *(const float4*)(A + (size_t)(bm + aRow) * lda + k0 + aCol);
        float4 bv = *(const float4*)(B + (size_t)(k0 + bRow) * ldb + bn + bCol);
        __syncthreads();
        As[aCol + 0][aRow] = av.x;
        As[aCol + 1][aRow] = av.y;
        As[aCol + 2][aRow] = av.z;
        As[aCol + 3][aRow] = av.w;
        *(float4*)&Bs[bRow][bCol] = bv;
        __syncthreads();
#pragma unroll
        for (int k = 0; k < 16; ++k) {
            float4 a4 = *(const float4*)&As[k][m0];
            float4 b4 = *(const float4*)&Bs[k][n0];
            float a[4] = {a4.x, a4.y, a4.z, a4.w};
            float b[4] = {b4.x, b4.y, b4.z, b4.w};
#pragma unroll
            for (int i = 0; i < 4; ++i)
#pragma unroll
                for (int j = 0; j < 4; ++j)
                    acc[i][j] = fmaf(a[i], b[j], acc[i][j]);
        }
    }

#pragma unroll
    for (int i = 0; i < 4; ++i) {
        int row = bm + m0 + i;
#pragma unroll
        for (int j = 0; j < 4; ++j) {
            int col = bn + n0 + j;
            float cv = acc[i][j] + bias[col];
            if (relu) cv = fmaxf(cv, 0.f);
            C[(size_t)row * ldc + col] = cv;
            if (C2) C2[(size_t)row * ldc + col] = cv;
        }
    }
}

// ---------------- launch ----------------
extern "C" void kernel_launch(void* const* d_in, const int* in_sizes, int n_in,
                              void* d_out, int out_size, void* d_ws, size_t ws_size,
                              hipStream_t stream)
{
    const float* x    = (const float*)d_in[0];
    const float* ex   = (const float*)d_in[1];
    const int*   nei  = (const int*)d_in[2];
    const int*   eil  = (const int*)d_in[3];
    const float* eal  = (const float*)d_in[4];
    const int*   eiu  = (const int*)d_in[5];
    const float* eau  = (const float*)d_in[6];
    const float* nW0  = (const float*)d_in[7];   // [3,64,128]  -> [192,128]
    const float* nb0  = (const float*)d_in[8];
    const float* nW1  = (const float*)d_in[9];   // [3,128,128] -> [384,128]
    const float* nb1  = (const float*)d_in[10];
    const float* fnW  = (const float*)d_in[11];  // [128,64]
    const float* fnb  = (const float*)d_in[12];
    const float* eWl0 = (const float*)d_in[13];  // [3,32,128]
    const float* eWu0 = (const float*)d_in[14];
    const float* eb0  = (const float*)d_in[15];
    const float* eWl1 = (const float*)d_in[16];  // [3,128,128]
    const float* eWu1 = (const float*)d_in[17];
    const float* eb1  = (const float*)d_in[18];
    const float* feW  = (const float*)d_in[19];  // [128,64]
    const float* feb  = (const float*)d_in[20];

    float* w = (float*)d_ws;
    size_t off = 0;
    auto alloc = [&](size_t n) { float* p = w + off; off += n; return p; };

    float* Z1n = alloc((size_t)4096 * 192);   // [x | Ax | A2x]
    float* Z2n = alloc((size_t)4096 * 384);   // [h | Ah | A2h]
    float* Z1e = alloc((size_t)8192 * 192);   // [e|Lle|Ll2e | e|Lue|Lu2e]
    float* Z2e = alloc((size_t)8192 * 768);
    u32* Abits = (u32*)alloc((size_t)NN * NN / 32);
    u32* keysL = (u32*)alloc(HCAP);
    u32* valsL = (u32*)alloc(HCAP);
    u32* keysU = (u32*)alloc(HCAP);
    u32* valsU = (u32*)alloc(HCAP);
    size_t memsetWords = off;                 // everything above needs zeroing
    float* h2   = alloc((size_t)4096 * 128);
    float* e2   = alloc((size_t)8192 * 128);
    float* eW1c = alloc(2 * 3 * 32 * 128);    // [192,128] = [eWl0; eWu0]
    float* eW2c = alloc(2 * 3 * 128 * 128);   // [768,128] = [eWl1; eWu1]
    float* nb0s = alloc(128);
    float* nb1s = alloc(128);
    u32* winA = (u32*)alloc(NE);
    u32* winL = (u32*)alloc(NLG);
    u32* winU = (u32*)alloc(NLG);

    hipMemsetAsync(d_ws, 0, memsetWords * 4, stream);

    // prep copies (fp32)
    SegPack P; int c = 0;
    auto seg = [&](const float* s, float* d, int n, int w_, int ld_, int t) {
        P.s[c++] = Seg{s, d, n, w_, ld_, t};
    };
    seg(x,    Z1n,          262144, 64, 192, 0);   // x -> Z1n[:,0:64]
    seg(ex,   Z1e,          262144, 32, 192, 0);   // edge_x -> Z1e[:,0:32]
    seg(ex,   Z1e + 96,     262144, 32, 192, 0);   // edge_x -> Z1e[:,96:128]
    seg(eWl0, eW1c,          12288, 12288, 12288, 0);
    seg(eWu0, eW1c + 12288,  12288, 12288, 12288, 0);
    seg(eWl1, eW2c,          49152, 49152, 49152, 0);
    seg(eWu1, eW2c + 49152,  49152, 49152, 49152, 0);
    seg(nb0,  nb0s, 128, 0, 0, 1);                 // sum over K_HOP
    seg(nb1,  nb1s, 128, 0, 0, 1);
    P.cnt = c;
    prep_kernel<<<dim3(512), dim3(256), 0, stream>>>(P);

    // dedup
    {
        int tot = NE + 2 * NLG;
        scatter_prep<<<dim3((tot + 255) / 256), dim3(256), 0, stream>>>(
            nei, Abits, winA, eil, keysL, valsL, eiu, keysU, valsU);
        winner_pass<<<dim3((2 * NLG + 255) / 256), dim3(256), 0, stream>>>(
            eil, keysL, valsL, winL, eiu, keysU, valsU, winU);
    }

    auto mkA = [&](const float* src, float* dst, int cols, int ld) {
        return SpSeg{nei, nullptr, winA, src, dst, NE, cols, ld, NE};
    };
    auto mkL = [&](const float* src, float* dst, int cols, int ld) {
        return SpSeg{eil, eal, winL, src, dst, NLG, cols, ld, NLG};
    };
    auto mkU = [&](const float* src, float* dst, int cols, int ld) {
        return SpSeg{eiu, eau, winU, src, dst, NLG, cols, ld, NLG};
    };
    auto spmm = [&](SpSeg a, SpSeg b, SpSeg cc) {
        int n0 = a.nnz * a.cols, n1 = b.nnz * b.cols, n2 = cc.nnz * cc.cols;
        int tot = n0 + n1 + n2;
        spmm3<<<dim3((tot + 255) / 256), dim3(256), 0, stream>>>(a, b, cc, n0, n1, n2);
    };
    auto gemm = [&](const float* A, int lda, const float* B, int ldb, const float* bias,
                    float* C, int ldc, float* C2, int M, int K, int N, int relu) {
        gemm_kernel<<<dim3(M / 64, N / 64), dim3(256), 0, stream>>>(
            A, lda, B, ldb, bias, C, ldc, C2, M, K, relu);
    };

    // ---- layer 1 hops ----
    spmm(mkA(Z1n, Z1n + 64, 64, 192),
         mkL(Z1e, Z1e + 32, 32, 192),
         mkU(Z1e + 96, Z1e + 128, 32, 192));
    spmm(mkA(Z1n + 64, Z1n + 128, 64, 192),
         mkL(Z1e + 32, Z1e + 64, 32, 192),
         mkU(Z1e + 128, Z1e + 160, 32, 192));

    // ---- layer 1 GEMMs (write into layer-2 Z z0 slots) ----
    gemm(Z1n, 192, nW0, 128, nb0s, Z2n, 384, nullptr, 4096, 192, 128, 1);
    gemm(Z1e, 192, eW1c, 128, eb0, Z2e, 768, Z2e + 384, 8192, 192, 128, 1);

    // ---- layer 2 hops ----
    spmm(mkA(Z2n, Z2n + 128, 128, 384),
         mkL(Z2e, Z2e + 128, 128, 768),
         mkU(Z2e + 384, Z2e + 512, 128, 768));
    spmm(mkA(Z2n + 128, Z2n + 256, 128, 384),
         mkL(Z2e + 128, Z2e + 256, 128, 768),
         mkU(Z2e + 512, Z2e + 640, 128, 768));

    // ---- layer 2 GEMMs ----
    gemm(Z2n, 384, nW1, 128, nb1s, h2, 128, nullptr, 4096, 384, 128, 1);
    gemm(Z2e, 768, eW2c, 128, eb1, e2, 128, nullptr, 8192, 768, 128, 1);

    // ---- heads -> fp32 out ----
    float* outf = (float*)d_out;
    gemm(h2, 128, fnW, 64, fnb, outf, 64, nullptr, 4096, 128, 64, 0);
    gemm(e2, 128, feW, 64, feb, outf + 262144, 64, nullptr, 8192, 128, 64, 0);
}

// Round 3
// 238.600 us; speedup vs baseline: 1.4339x; 1.4339x over previous
//
#include <hip/hip_runtime.h>

#define NN 4096
#define NE 8192
#define NLG 32768
#define HCAP 131072
#define HMASK (HCAP - 1)

typedef unsigned int u32;
typedef unsigned short u16;
typedef __attribute__((ext_vector_type(4))) float f32x4;
typedef __attribute__((ext_vector_type(8))) short bf16x8;

__device__ __forceinline__ float bf2f(u16 u) { return __uint_as_float(((u32)u) << 16); }
__device__ __forceinline__ u16 f2bf(float f) {
    u32 x = __float_as_uint(f);
    return (u16)((x + 0x7fffu + ((x >> 16) & 1u)) >> 16);  // RNE
}

// ---------------- prep: fp32 -> bf16 copies / transposes / bias-sum ----------------
// type 0: copy fp32[n] (logical rows of width w) -> bf16 at r*ld+c
// type 1: bias sum over 3 rows of [3,n] -> fp32
// type 2: weight transpose: i = nn*Kp + k ; dst16[nn*ld + kofs + k] = src[k*Nw + nn]
struct Seg { const float* src; u16* d16; float* d32; int n; int w; int ld; int kofs; int type; };
struct SegPack { Seg s[13]; int cnt; };

__global__ __launch_bounds__(256) void prep_kernel(SegPack P) {
    int i0 = blockIdx.x * blockDim.x + threadIdx.x;
    int stride = gridDim.x * blockDim.x;
    for (int si = 0; si < P.cnt; ++si) {
        Seg sg = P.s[si];
        if (sg.type == 0) {
            for (int i = i0; i < sg.n; i += stride) {
                int r = i / sg.w, c = i - r * sg.w;
                sg.d16[(size_t)r * sg.ld + c] = f2bf(sg.src[i]);
            }
        } else if (sg.type == 1) {
            for (int i = i0; i < sg.n; i += stride) {
                float a = 0.f;
#pragma unroll
                for (int k = 0; k < 3; ++k) a += sg.src[k * sg.n + i];
                sg.d32[i] = a;
            }
        } else {
            int Kp = sg.w, Nw = sg.n / Kp;
            for (int i = i0; i < sg.n; i += stride) {
                int nn = i / Kp, k = i - nn * Kp;
                sg.d16[(size_t)nn * sg.ld + sg.kofs + k] = f2bf(sg.src[(size_t)k * Nw + nn]);
            }
        }
    }
}

// ---------------- dedup: bitmask for A, hash (last-occurrence wins) for Ll/Lu ----------------
__device__ __forceinline__ u32 ht_hash(u32 slot) { return (slot * 2654435761u) & HMASK; }

__device__ __forceinline__ void ht_insert(u32* keys, u32* vals, u32 slot, u32 eid) {
    u32 key = slot + 1u;
    u32 h = ht_hash(slot);
    for (;;) {
        u32 k = keys[h];
        if (k == key) { atomicMax(&vals[h], eid + 1u); return; }
        if (k == 0u) {
            u32 old = atomicCAS(&keys[h], 0u, key);
            if (old == 0u || old == key) { atomicMax(&vals[h], eid + 1u); return; }
            continue;
        }
        h = (h + 1u) & HMASK;
    }
}

__device__ __forceinline__ u32 ht_find(const u32* keys, u32 slot) {
    u32 key = slot + 1u;
    u32 h = ht_hash(slot);
    for (;;) { if (keys[h] == key) return h; h = (h + 1u) & HMASK; }
}

__global__ __launch_bounds__(256) void scatter_prep(
    const int* nei, u32* Abits, u32* winA,
    const int* eil, u32* keysL, u32* valsL,
    const int* eiu, u32* keysU, u32* valsU)
{
    int id = blockIdx.x * blockDim.x + threadIdx.x;
    if (id < NE) {
        u32 u = (u32)nei[id], v = (u32)nei[NE + id];
        u32 slot = u * (u32)NN + v;
        u32 old = atomicOr(&Abits[slot >> 5], 1u << (slot & 31));
        winA[id] = ((old >> (slot & 31)) & 1u) ? 0u : 1u;
    } else if (id < NE + NLG) {
        int e = id - NE;
        ht_insert(keysL, valsL, (u32)eil[e] * (u32)NE + (u32)eil[NLG + e], (u32)e);
    } else if (id < NE + 2 * NLG) {
        int e = id - NE - NLG;
        ht_insert(keysU, valsU, (u32)eiu[e] * (u32)NE + (u32)eiu[NLG + e], (u32)e);
    }
}

struct WHArgs {
    const int* nei; const u32* winA; u32* cntA;
    const int* eil; const u32* keysL; const u32* valsL; u32* winL; u32* cntL;
    const int* eiu; const u32* keysU; const u32* valsU; u32* winU; u32* cntU;
};

__global__ __launch_bounds__(256) void winner_hist(WHArgs A) {
    int id = blockIdx.x * blockDim.x + threadIdx.x;
    if (id < NE) {
        if (A.winA[id]) atomicAdd(&A.cntA[A.nei[id]], 1u);
    } else if (id < NE + NLG) {
        int e = id - NE;
        u32 h = ht_find(A.keysL, (u32)A.eil[e] * (u32)NE + (u32)A.eil[NLG + e]);
        u32 win = (A.valsL[h] == (u32)e + 1u) ? 1u : 0u;
        A.winL[e] = win;
        if (win) atomicAdd(&A.cntL[A.eil[e]], 1u);
    } else if (id < NE + 2 * NLG) {
        int e = id - NE - NLG;
        u32 h = ht_find(A.keysU, (u32)A.eiu[e] * (u32)NE + (u32)A.eiu[NLG + e]);
        u32 win = (A.valsU[h] == (u32)e + 1u) ? 1u : 0u;
        A.winU[e] = win;
        if (win) atomicAdd(&A.cntU[A.eiu[e]], 1u);
    }
}

// ---------------- exclusive scan (one block per array) ----------------
__global__ __launch_bounds__(1024) void scan3(const u32* cntA, u32* ptrA,
                                              const u32* cntL, u32* ptrL,
                                              const u32* cntU, u32* ptrU)
{
    __shared__ u32 sm[1024];
    const u32* cnt; u32* ptr; int n;
    if (blockIdx.x == 0) { cnt = cntA; ptr = ptrA; n = NN; }
    else if (blockIdx.x == 1) { cnt = cntL; ptr = ptrL; n = NE; }
    else { cnt = cntU; ptr = ptrU; n = NE; }
    int t = threadIdx.x;
    int chunk = n >> 10;  // 4 or 8
    u32 loc[8];
    u32 base = (u32)t * chunk, sum = 0;
    for (int i = 0; i < chunk; ++i) { loc[i] = cnt[base + i]; sum += loc[i]; }
    sm[t] = sum; __syncthreads();
    for (int off = 1; off < 1024; off <<= 1) {
        u32 v = (t >= off) ? sm[t - off] : 0u;
        __syncthreads();
        sm[t] += v;
        __syncthreads();
    }
    u32 ex = (t == 0) ? 0u : sm[t - 1];
    for (int i = 0; i < chunk; ++i) { ptr[base + i] = ex; ex += loc[i]; }
    if (t == 1023) ptr[n] = ex;
}

// ---------------- CSR fill ----------------
struct CFArgs {
    const int* nei; const u32* winA; const u32* ptrA; u32* fillA; u32* colA;
    const int* eil; const float* eal; const u32* winL; const u32* ptrL; u32* fillL; u32* colL; float* wL;
    const int* eiu; const float* eau; const u32* winU; const u32* ptrU; u32* fillU; u32* colU; float* wU;
};

__global__ __launch_bounds__(256) void csr_fill(CFArgs A) {
    int id = blockIdx.x * blockDim.x + threadIdx.x;
    if (id < NE) {
        if (A.winA[id]) {
            int u = A.nei[id];
            u32 pos = A.ptrA[u] + atomicAdd(&A.fillA[u], 1u);
            A.colA[pos] = (u32)A.nei[NE + id];
        }
    } else if (id < NE + NLG) {
        int e = id - NE;
        if (A.winL[e]) {
            int u = A.eil[e];
            u32 pos = A.ptrL[u] + atomicAdd(&A.fillL[u], 1u);
            A.colL[pos] = (u32)A.eil[NLG + e];
            A.wL[pos] = A.eal[e];
        }
    } else if (id < NE + 2 * NLG) {
        int e = id - NE - NLG;
        if (A.winU[e]) {
            int u = A.eiu[e];
            u32 pos = A.ptrU[u] + atomicAdd(&A.fillU[u], 1u);
            A.colU[pos] = (u32)A.eiu[NLG + e];
            A.wU[pos] = A.eau[e];
        }
    }
}

// ---------------- gather SpMM (bf16 src/dst, fp32 weights+acc), 3 fused segments ----------------
struct GSeg { const u32* ptr; const u32* col; const float* wgt; const u16* src; u16* dst;
              int n; int shift; int mask; int ld; };

__global__ __launch_bounds__(256) void spmm_gather(GSeg a, GSeg b, GSeg c) {
    int id = blockIdx.x * blockDim.x + threadIdx.x;
    GSeg s; int t;
    if (id < a.n) { s = a; t = id; }
    else if (id < a.n + b.n) { s = b; t = id - a.n; }
    else if (id < a.n + b.n + c.n) { s = c; t = id - a.n - b.n; }
    else return;
    int row = t >> s.shift, col = t & s.mask;
    u32 j0 = s.ptr[row], j1 = s.ptr[row + 1];
    float acc = 0.f;
    for (u32 j = j0; j < j1; ++j) {
        u32 v = s.col[j];
        float wv = s.wgt ? s.wgt[j] : 1.0f;
        acc += wv * bf2f(s.src[(size_t)v * s.ld + col]);
    }
    s.dst[(size_t)row * s.ld + col] = f2bf(acc);
}

// ---------------- MFMA GEMM: C[M,N] = A[M,K] @ WT[N,K]^T + bias (two fused problems) ----------------
// One wave per 16-row x 64-col tile. A row-major bf16, WT row-major [N,K] bf16.
struct GemmArgs { const u16* A; int lda; const u16* WT; int K; const float* bias;
                  u16* dst; u16* dst2; float* dstf; int ldd; int relu; int mblocks; };

__global__ __launch_bounds__(64) void mfma_gemm2(GemmArgs g0, GemmArgs g1) {
    GemmArgs g = (blockIdx.x < (u32)g0.mblocks) ? g0 : g1;
    int bx = (blockIdx.x < (u32)g0.mblocks) ? blockIdx.x : blockIdx.x - g0.mblocks;
    int lane = threadIdx.x;
    int m0 = bx * 16;
    int n0 = blockIdx.y * 64;
    int row = lane & 15;
    int koff = (lane >> 4) * 8;
    f32x4 acc[4] = {};
    const u16* Ap = g.A + (size_t)(m0 + row) * g.lda + koff;
    const u16* Wp = g.WT + (size_t)(n0 + row) * g.K + koff;
    size_t wstride = (size_t)16 * g.K;
    for (int k0 = 0; k0 < g.K; k0 += 32) {
        bf16x8 af = *(const bf16x8*)(Ap + k0);
#pragma unroll
        for (int nt = 0; nt < 4; ++nt) {
            bf16x8 bf = *(const bf16x8*)(Wp + nt * wstride + k0);
            acc[nt] = __builtin_amdgcn_mfma_f32_16x16x32_bf16(af, bf, acc[nt], 0, 0, 0);
        }
    }
    int orow = m0 + (lane >> 4) * 4;
#pragma unroll
    for (int nt = 0; nt < 4; ++nt) {
        int col = n0 + nt * 16 + row;
        float bv = g.bias[col];
#pragma unroll
        for (int r = 0; r < 4; ++r) {
            float v = acc[nt][r] + bv;
            if (g.relu) v = fmaxf(v, 0.f);
            size_t o = (size_t)(orow + r) * g.ldd + col;
            if (g.dstf) { g.dstf[o] = v; }
            else { u16 q = f2bf(v); g.dst[o] = q; if (g.dst2) g.dst2[o] = q; }
        }
    }
}

// ---------------- launch ----------------
extern "C" void kernel_launch(void* const* d_in, const int* in_sizes, int n_in,
                              void* d_out, int out_size, void* d_ws, size_t ws_size,
                              hipStream_t stream)
{
    const float* x    = (const float*)d_in[0];
    const float* ex   = (const float*)d_in[1];
    const int*   nei  = (const int*)d_in[2];
    const int*   eil  = (const int*)d_in[3];
    const float* eal  = (const float*)d_in[4];
    const int*   eiu  = (const int*)d_in[5];
    const float* eau  = (const float*)d_in[6];
    const float* nW0  = (const float*)d_in[7];
    const float* nb0  = (const float*)d_in[8];
    const float* nW1  = (const float*)d_in[9];
    const float* nb1  = (const float*)d_in[10];
    const float* fnW  = (const float*)d_in[11];
    const float* fnb  = (const float*)d_in[12];
    const float* eWl0 = (const float*)d_in[13];
    const float* eWu0 = (const float*)d_in[14];
    const float* eb0  = (const float*)d_in[15];
    const float* eWl1 = (const float*)d_in[16];
    const float* eWu1 = (const float*)d_in[17];
    const float* eb1  = (const float*)d_in[18];
    const float* feW  = (const float*)d_in[19];
    const float* feb  = (const float*)d_in[20];

    char* wsb = (char*)d_ws;
    size_t off = 0;
    auto alloc = [&](size_t bytes) { void* p = wsb + off; off += (bytes + 255) & ~(size_t)255; return p; };

    // ---- zeroed region first ----
    u32* Abits = (u32*)alloc((size_t)NN * NN / 8);   // 2 MB
    u32* keysL = (u32*)alloc(HCAP * 4);
    u32* valsL = (u32*)alloc(HCAP * 4);
    u32* keysU = (u32*)alloc(HCAP * 4);
    u32* valsU = (u32*)alloc(HCAP * 4);
    u32* cntA  = (u32*)alloc(NN * 4);
    u32* cntL  = (u32*)alloc(NE * 4);
    u32* cntU  = (u32*)alloc(NE * 4);
    u32* fillA = (u32*)alloc(NN * 4);
    u32* fillL = (u32*)alloc(NE * 4);
    u32* fillU = (u32*)alloc(NE * 4);
    size_t zbytes = off;

    // ---- rest ----
    u32* winA = (u32*)alloc(NE * 4);
    u32* winL = (u32*)alloc(NLG * 4);
    u32* winU = (u32*)alloc(NLG * 4);
    u32* ptrA = (u32*)alloc((NN + 1) * 4);
    u32* ptrL = (u32*)alloc((NE + 1) * 4);
    u32* ptrU = (u32*)alloc((NE + 1) * 4);
    u32* colA = (u32*)alloc(NE * 4);
    u32* colL = (u32*)alloc(NLG * 4);
    u32* colU = (u32*)alloc(NLG * 4);
    float* wL = (float*)alloc(NLG * 4);
    float* wU = (float*)alloc(NLG * 4);

    u16* Zb1n = (u16*)alloc((size_t)4096 * 192 * 2);
    u16* Zb1e = (u16*)alloc((size_t)8192 * 192 * 2);
    u16* Zb2n = (u16*)alloc((size_t)4096 * 384 * 2);
    u16* Zb2e = (u16*)alloc((size_t)8192 * 768 * 2);
    u16* h2b  = (u16*)alloc((size_t)4096 * 128 * 2);
    u16* e2b  = (u16*)alloc((size_t)8192 * 128 * 2);

    u16* nW0T = (u16*)alloc((size_t)128 * 192 * 2);
    u16* nW1T = (u16*)alloc((size_t)128 * 384 * 2);
    u16* eW1T = (u16*)alloc((size_t)128 * 192 * 2);
    u16* eW2T = (u16*)alloc((size_t)128 * 768 * 2);
    u16* fnWT = (u16*)alloc((size_t)64 * 128 * 2);
    u16* feWT = (u16*)alloc((size_t)64 * 128 * 2);
    float* nb0s = (float*)alloc(128 * 4);
    float* nb1s = (float*)alloc(128 * 4);

    hipMemsetAsync(d_ws, 0, zbytes, stream);

    // ---- prep ----
    SegPack P; int c = 0;
    auto segc = [&](const float* s, u16* d, int n, int w_, int ld_) {          // type 0
        P.s[c++] = Seg{s, d, nullptr, n, w_, ld_, 0, 0};
    };
    auto segt = [&](const float* s, u16* d, int Kp, int N, int ldT, int kofs) { // type 2
        P.s[c++] = Seg{s, d, nullptr, N * Kp, Kp, ldT, kofs, 2};
    };
    segc(x,  Zb1n,      262144, 64, 192);
    segc(ex, Zb1e,      262144, 32, 192);
    segc(ex, Zb1e + 96, 262144, 32, 192);
    segt(nW0,  nW0T, 192, 128, 192, 0);
    segt(nW1,  nW1T, 384, 128, 384, 0);
    segt(eWl0, eW1T,  96, 128, 192, 0);
    segt(eWu0, eW1T,  96, 128, 192, 96);
    segt(eWl1, eW2T, 384, 128, 768, 0);
    segt(eWu1, eW2T, 384, 128, 768, 384);
    segt(fnW,  fnWT, 128,  64, 128, 0);
    segt(feW,  feWT, 128,  64, 128, 0);
    P.s[c++] = Seg{nb0, nullptr, nb0s, 128, 0, 0, 0, 1};
    P.s[c++] = Seg{nb1, nullptr, nb1s, 128, 0, 0, 0, 1};
    P.cnt = c;
    prep_kernel<<<dim3(512), dim3(256), 0, stream>>>(P);

    // ---- dedup + CSR build ----
    int tot = NE + 2 * NLG;
    scatter_prep<<<dim3((tot + 255) / 256), dim3(256), 0, stream>>>(
        nei, Abits, winA, eil, keysL, valsL, eiu, keysU, valsU);
    WHArgs wh{nei, winA, cntA, eil, keysL, valsL, winL, cntL, eiu, keysU, valsU, winU, cntU};
    winner_hist<<<dim3((tot + 255) / 256), dim3(256), 0, stream>>>(wh);
    scan3<<<dim3(3), dim3(1024), 0, stream>>>(cntA, ptrA, cntL, ptrL, cntU, ptrU);
    CFArgs cf{nei, winA, ptrA, fillA, colA,
              eil, eal, winL, ptrL, fillL, colL, wL,
              eiu, eau, winU, ptrU, fillU, colU, wU};
    csr_fill<<<dim3((tot + 255) / 256), dim3(256), 0, stream>>>(cf);

    // ---- helpers ----
    auto gseg = [&](const u32* ptr, const u32* col, const float* wgt,
                    const u16* src, u16* dst, int rows, int cshift, int ld) {
        return GSeg{ptr, col, wgt, src, dst, rows << cshift, cshift, (1 << cshift) - 1, ld};
    };
    auto spmm = [&](GSeg a, GSeg b, GSeg cc) {
        int n = a.n + b.n + cc.n;
        spmm_gather<<<dim3((n + 255) / 256), dim3(256), 0, stream>>>(a, b, cc);
    };
    auto gemm2 = [&](GemmArgs g0, GemmArgs g1, int ncols) {
        mfma_gemm2<<<dim3(g0.mblocks + g1.mblocks, ncols / 64), dim3(64), 0, stream>>>(g0, g1);
    };

    // ---- layer 1 hops ----
    spmm(gseg(ptrA, colA, nullptr, Zb1n,      Zb1n + 64,  NN, 6, 192),
         gseg(ptrL, colL, wL,      Zb1e,      Zb1e + 32,  NE, 5, 192),
         gseg(ptrU, colU, wU,      Zb1e + 96, Zb1e + 128, NE, 5, 192));
    spmm(gseg(ptrA, colA, nullptr, Zb1n + 64,  Zb1n + 128, NN, 6, 192),
         gseg(ptrL, colL, wL,      Zb1e + 32,  Zb1e + 64,  NE, 5, 192),
         gseg(ptrU, colU, wU,      Zb1e + 128, Zb1e + 160, NE, 5, 192));

    // ---- layer 1 GEMMs ----
    gemm2(GemmArgs{Zb1n, 192, nW0T, 192, nb0s, Zb2n, nullptr, nullptr, 384, 1, 256},
          GemmArgs{Zb1e, 192, eW1T, 192, eb0,  Zb2e, Zb2e + 384, nullptr, 768, 1, 512}, 128);

    // ---- layer 2 hops ----
    spmm(gseg(ptrA, colA, nullptr, Zb2n,       Zb2n + 128, NN, 7, 384),
         gseg(ptrL, colL, wL,      Zb2e,       Zb2e + 128, NE, 7, 768),
         gseg(ptrU, colU, wU,      Zb2e + 384, Zb2e + 512, NE, 7, 768));
    spmm(gseg(ptrA, colA, nullptr, Zb2n + 128, Zb2n + 256, NN, 7, 384),
         gseg(ptrL, colL, wL,      Zb2e + 128, Zb2e + 256, NE, 7, 768),
         gseg(ptrU, colU, wU,      Zb2e + 512, Zb2e + 640, NE, 7, 768));

    // ---- layer 2 GEMMs ----
    gemm2(GemmArgs{Zb2n, 384, nW1T, 384, nb1s, h2b, nullptr, nullptr, 128, 1, 256},
          GemmArgs{Zb2e, 768, eW2T, 768, eb1,  e2b, nullptr, nullptr, 128, 1, 512}, 128);

    // ---- heads -> fp32 d_out ----
    float* outf = (float*)d_out;
    gemm2(GemmArgs{h2b, 128, fnWT, 128, fnb, nullptr, nullptr, outf,          64, 0, 256},
          GemmArgs{e2b, 128, feWT, 128, feb, nullptr, nullptr, outf + 262144, 64, 0, 512}, 64);
}

// Round 4
// 222.580 us; speedup vs baseline: 1.5371x; 1.0720x over previous
//
#include <hip/hip_runtime.h>

#define NN 4096
#define NE 8192
#define NLG 32768
#define HCA 16384     // A hash capacity (<=8192 keys, load factor .5)
#define HCL 65536     // L/U hash capacity (<=32768 keys, lf .5)

typedef unsigned int u32;
typedef unsigned short u16;
typedef __attribute__((ext_vector_type(4))) float f32x4;
typedef __attribute__((ext_vector_type(8))) short bf16x8;
typedef __attribute__((ext_vector_type(8))) unsigned short u16x8;
typedef __attribute__((ext_vector_type(4))) unsigned short u16x4;
typedef __attribute__((ext_vector_type(4))) unsigned int u32x4;

__device__ __forceinline__ float bf2f(u16 u) { return __uint_as_float(((u32)u) << 16); }
__device__ __forceinline__ u16 f2bf(float f) {
    u32 x = __float_as_uint(f);
    return (u16)((x + 0x7fffu + ((x >> 16) & 1u)) >> 16);  // RNE
}

// ---------------- prep: zero + fp32 -> bf16 copies / transposes / bias-sum ----------------
// type 0: vec4 copy fp32[n] (rows of width w) -> bf16 at r*ld+c   (n,w,ld multiples of 4)
// type 1: bias sum over 3 rows of [3,n] -> fp32
// type 2: weight transpose: i = nn*Kp + k ; d16[nn*ld + kofs + k] = src[k*Nw + nn]
// type 3: zero u32[n] via vec4 (n multiple of 4)
struct Seg { const float* src; u16* d16; u32* dz; float* d32; int n; int w; int ld; int kofs; int type; };
struct SegPack { Seg s[14]; int cnt; };

__global__ __launch_bounds__(256) void prep_kernel(SegPack P) {
    int i0 = blockIdx.x * blockDim.x + threadIdx.x;
    int stride = gridDim.x * blockDim.x;
    for (int si = 0; si < P.cnt; ++si) {
        Seg sg = P.s[si];
        if (sg.type == 0) {
            int n4 = sg.n >> 2, w4 = sg.w >> 2;
            for (int i = i0; i < n4; i += stride) {
                int r = i / w4, c4 = i - r * w4;
                f32x4 v = *(const f32x4*)(sg.src + (size_t)i * 4);
                u16x4 o;
#pragma unroll
                for (int e = 0; e < 4; ++e) o[e] = f2bf(v[e]);
                *(u16x4*)(sg.d16 + (size_t)r * sg.ld + c4 * 4) = o;
            }
        } else if (sg.type == 1) {
            for (int i = i0; i < sg.n; i += stride) {
                float a = 0.f;
#pragma unroll
                for (int k = 0; k < 3; ++k) a += sg.src[k * sg.n + i];
                sg.d32[i] = a;
            }
        } else if (sg.type == 2) {
            int Kp = sg.w, Nw = sg.n / Kp;
            for (int i = i0; i < sg.n; i += stride) {
                int nn = i / Kp, k = i - nn * Kp;
                sg.d16[(size_t)nn * sg.ld + sg.kofs + k] = f2bf(sg.src[(size_t)k * Nw + nn]);
            }
        } else {
            int n4 = sg.n >> 2;
            u32x4 z = {0u, 0u, 0u, 0u};
            for (int i = i0; i < n4; i += stride) *(u32x4*)(sg.dz + (size_t)i * 4) = z;
        }
    }
}

// ---------------- hash insert (dedup; last-occurrence wins via max eid) ----------------
__device__ __forceinline__ void ht_insert(u32* keys, u32* vals, u32 mask, u32 slot, u32 eid) {
    u32 key = slot + 1u;
    u32 h = (slot * 2654435761u) & mask;
    for (;;) {
        u32 k = keys[h];
        if (k == key) { if (vals) atomicMax(&vals[h], eid + 1u); return; }
        if (k == 0u) {
            u32 old = atomicCAS(&keys[h], 0u, key);
            if (old == 0u || old == key) { if (vals) atomicMax(&vals[h], eid + 1u); return; }
            continue;  // re-check claimed bucket
        }
        h = (h + 1u) & mask;
    }
}

__global__ __launch_bounds__(256) void insert_kernel(
    const int* nei, u32* keysA,
    const int* eil, u32* keysL, u32* valsL,
    const int* eiu, u32* keysU, u32* valsU)
{
    int id = blockIdx.x * blockDim.x + threadIdx.x;
    if (id < NE) {
        ht_insert(keysA, nullptr, HCA - 1, (u32)nei[id] * (u32)NN + (u32)nei[NE + id], 0u);
    } else if (id < NE + NLG) {
        int e = id - NE;
        ht_insert(keysL, valsL, HCL - 1, (u32)eil[e] * (u32)NE + (u32)eil[NLG + e], (u32)e);
    } else if (id < NE + 2 * NLG) {
        int e = id - NE - NLG;
        ht_insert(keysU, valsU, HCL - 1, (u32)eiu[e] * (u32)NE + (u32)eiu[NLG + e], (u32)e);
    }
}

// ---------------- hist: iterate hash slots, count rows ----------------
__global__ __launch_bounds__(256) void hist_kernel(
    const u32* keysA, u32* cntA,
    const u32* keysL, u32* cntL,
    const u32* keysU, u32* cntU)
{
    int id = blockIdx.x * blockDim.x + threadIdx.x;
    if (id < HCA) {
        u32 k = keysA[id];
        if (k) atomicAdd(&cntA[(k - 1u) >> 12], 1u);
    } else if (id < HCA + HCL) {
        u32 k = keysL[id - HCA];
        if (k) atomicAdd(&cntL[(k - 1u) >> 13], 1u);
    } else if (id < HCA + 2 * HCL) {
        u32 k = keysU[id - HCA - HCL];
        if (k) atomicAdd(&cntU[(k - 1u) >> 13], 1u);
    }
}

// ---------------- exclusive scan: 3 blocks x 256 threads ----------------
__global__ __launch_bounds__(256) void scan3(const u32* cntA, u32* ptrA,
                                             const u32* cntL, u32* ptrL,
                                             const u32* cntU, u32* ptrU)
{
    __shared__ u32 sm[256];
    const u32* cnt; u32* ptr; int n;
    if (blockIdx.x == 0) { cnt = cntA; ptr = ptrA; n = NN; }
    else if (blockIdx.x == 1) { cnt = cntL; ptr = ptrL; n = NE; }
    else { cnt = cntU; ptr = ptrU; n = NE; }
    int t = threadIdx.x;
    int chunk = n >> 8;  // 16 or 32
    u32 loc[32];
    u32 base = (u32)t * chunk, sum = 0;
    for (int i = 0; i < chunk; ++i) { loc[i] = cnt[base + i]; sum += loc[i]; }
    sm[t] = sum; __syncthreads();
    for (int off = 1; off < 256; off <<= 1) {
        u32 v = (t >= off) ? sm[t - off] : 0u;
        __syncthreads();
        sm[t] += v;
        __syncthreads();
    }
    u32 ex = (t == 0) ? 0u : sm[t - 1];
    for (int i = 0; i < chunk; ++i) { ptr[base + i] = ex; ex += loc[i]; }
    if (t == 255) ptr[n] = ex;
}

// ---------------- fill: iterate hash slots, place into CSR ----------------
struct FillArgs {
    const u32* keysA; const u32* ptrA; u32* fillA; u32* colA;
    const u32* keysL; const u32* valsL; const float* eal; const u32* ptrL; u32* fillL; u32* colL; float* wL;
    const u32* keysU; const u32* valsU; const float* eau; const u32* ptrU; u32* fillU; u32* colU; float* wU;
};

__global__ __launch_bounds__(256) void fill_kernel(FillArgs A) {
    int id = blockIdx.x * blockDim.x + threadIdx.x;
    if (id < HCA) {
        u32 k = A.keysA[id];
        if (k) {
            u32 u = (k - 1u) >> 12, v = (k - 1u) & 4095u;
            u32 pos = A.ptrA[u] + atomicAdd(&A.fillA[u], 1u);
            A.colA[pos] = v;
        }
    } else if (id < HCA + HCL) {
        int h = id - HCA;
        u32 k = A.keysL[h];
        if (k) {
            u32 p = (k - 1u) >> 13, q = (k - 1u) & 8191u;
            u32 pos = A.ptrL[p] + atomicAdd(&A.fillL[p], 1u);
            A.colL[pos] = q;
            A.wL[pos] = A.eal[A.valsL[h] - 1u];
        }
    } else if (id < HCA + 2 * HCL) {
        int h = id - HCA - HCL;
        u32 k = A.keysU[h];
        if (k) {
            u32 p = (k - 1u) >> 13, q = (k - 1u) & 8191u;
            u32 pos = A.ptrU[p] + atomicAdd(&A.fillU[p], 1u);
            A.colU[pos] = q;
            A.wU[pos] = A.eau[A.valsU[h] - 1u];
        }
    }
}

// ---------------- gather SpMM: 8 bf16 cols per thread, 3 fused segments ----------------
struct GSeg { const u32* ptr; const u32* col; const float* wgt; const u16* src; u16* dst;
              int n; int shift; int mask; int ld; };

__global__ __launch_bounds__(256) void spmm_gather(GSeg a, GSeg b, GSeg c) {
    int id = blockIdx.x * blockDim.x + threadIdx.x;
    GSeg s; int t;
    if (id < a.n) { s = a; t = id; }
    else if (id < a.n + b.n) { s = b; t = id - a.n; }
    else if (id < a.n + b.n + c.n) { s = c; t = id - a.n - b.n; }
    else return;
    int row = t >> s.shift, g = t & s.mask;
    u32 j0 = s.ptr[row], j1 = s.ptr[row + 1];
    float acc[8] = {};
    const u16* srcg = s.src + g * 8;
    for (u32 j = j0; j < j1; ++j) {
        u32 v = s.col[j];
        float wv = s.wgt ? s.wgt[j] : 1.0f;
        u16x8 xv = *(const u16x8*)(srcg + (size_t)v * s.ld);
#pragma unroll
        for (int e = 0; e < 8; ++e) acc[e] = fmaf(wv, bf2f(xv[e]), acc[e]);
    }
    u16x8 o;
#pragma unroll
    for (int e = 0; e < 8; ++e) o[e] = f2bf(acc[e]);
    *(u16x8*)(s.dst + (size_t)row * s.ld + g * 8) = o;
}

// ---------------- MFMA GEMM: C[M,N] = A[M,K] @ WT[N,K]^T + bias (two fused problems) ----------------
struct GemmArgs { const u16* A; int lda; const u16* WT; int K; const float* bias;
                  u16* dst; u16* dst2; float* dstf; int ldd; int relu; int mblocks; };

__global__ __launch_bounds__(64) void mfma_gemm2(GemmArgs g0, GemmArgs g1) {
    GemmArgs g = (blockIdx.x < (u32)g0.mblocks) ? g0 : g1;
    int bx = (blockIdx.x < (u32)g0.mblocks) ? blockIdx.x : blockIdx.x - g0.mblocks;
    int lane = threadIdx.x;
    int m0 = bx * 16;
    int n0 = blockIdx.y * 64;
    int row = lane & 15;
    int koff = (lane >> 4) * 8;
    f32x4 acc[4] = {};
    const u16* Ap = g.A + (size_t)(m0 + row) * g.lda + koff;
    const u16* Wp = g.WT + (size_t)(n0 + row) * g.K + koff;
    size_t wstride = (size_t)16 * g.K;
    for (int k0 = 0; k0 < g.K; k0 += 32) {
        bf16x8 af = *(const bf16x8*)(Ap + k0);
#pragma unroll
        for (int nt = 0; nt < 4; ++nt) {
            bf16x8 bf = *(const bf16x8*)(Wp + nt * wstride + k0);
            acc[nt] = __builtin_amdgcn_mfma_f32_16x16x32_bf16(af, bf, acc[nt], 0, 0, 0);
        }
    }
    int orow = m0 + (lane >> 4) * 4;
#pragma unroll
    for (int nt = 0; nt < 4; ++nt) {
        int col = n0 + nt * 16 + row;
        float bv = g.bias[col];
#pragma unroll
        for (int r = 0; r < 4; ++r) {
            float v = acc[nt][r] + bv;
            if (g.relu) v = fmaxf(v, 0.f);
            size_t o = (size_t)(orow + r) * g.ldd + col;
            if (g.dstf) { g.dstf[o] = v; }
            else { u16 q = f2bf(v); g.dst[o] = q; if (g.dst2) g.dst2[o] = q; }
        }
    }
}

// ---------------- launch ----------------
extern "C" void kernel_launch(void* const* d_in, const int* in_sizes, int n_in,
                              void* d_out, int out_size, void* d_ws, size_t ws_size,
                              hipStream_t stream)
{
    const float* x    = (const float*)d_in[0];
    const float* ex   = (const float*)d_in[1];
    const int*   nei  = (const int*)d_in[2];
    const int*   eil  = (const int*)d_in[3];
    const float* eal  = (const float*)d_in[4];
    const int*   eiu  = (const int*)d_in[5];
    const float* eau  = (const float*)d_in[6];
    const float* nW0  = (const float*)d_in[7];
    const float* nb0  = (const float*)d_in[8];
    const float* nW1  = (const float*)d_in[9];
    const float* nb1  = (const float*)d_in[10];
    const float* fnW  = (const float*)d_in[11];
    const float* fnb  = (const float*)d_in[12];
    const float* eWl0 = (const float*)d_in[13];
    const float* eWu0 = (const float*)d_in[14];
    const float* eb0  = (const float*)d_in[15];
    const float* eWl1 = (const float*)d_in[16];
    const float* eWu1 = (const float*)d_in[17];
    const float* eb1  = (const float*)d_in[18];
    const float* feW  = (const float*)d_in[19];
    const float* feb  = (const float*)d_in[20];

    char* wsb = (char*)d_ws;
    size_t off = 0;
    auto alloc = [&](size_t bytes) { void* p = wsb + off; off += (bytes + 255) & ~(size_t)255; return p; };

    // ---- zeroed region (zeroed by prep_kernel seg type 3) ----
    u32* keysA = (u32*)alloc(HCA * 4);
    u32* keysL = (u32*)alloc(HCL * 4);
    u32* valsL = (u32*)alloc(HCL * 4);
    u32* keysU = (u32*)alloc(HCL * 4);
    u32* valsU = (u32*)alloc(HCL * 4);
    u32* cntA  = (u32*)alloc(NN * 4);
    u32* cntL  = (u32*)alloc(NE * 4);
    u32* cntU  = (u32*)alloc(NE * 4);
    u32* fillA = (u32*)alloc(NN * 4);
    u32* fillL = (u32*)alloc(NE * 4);
    u32* fillU = (u32*)alloc(NE * 4);
    size_t zbytes = off;

    // ---- rest ----
    u32* ptrA = (u32*)alloc((NN + 1) * 4);
    u32* ptrL = (u32*)alloc((NE + 1) * 4);
    u32* ptrU = (u32*)alloc((NE + 1) * 4);
    u32* colA = (u32*)alloc(NE * 4);
    u32* colL = (u32*)alloc(NLG * 4);
    u32* colU = (u32*)alloc(NLG * 4);
    float* wL = (float*)alloc(NLG * 4);
    float* wU = (float*)alloc(NLG * 4);

    u16* Zb1n = (u16*)alloc((size_t)4096 * 192 * 2);
    u16* Zb1e = (u16*)alloc((size_t)8192 * 192 * 2);
    u16* Zb2n = (u16*)alloc((size_t)4096 * 384 * 2);
    u16* Zb2e = (u16*)alloc((size_t)8192 * 768 * 2);
    u16* h2b  = (u16*)alloc((size_t)4096 * 128 * 2);
    u16* e2b  = (u16*)alloc((size_t)8192 * 128 * 2);

    u16* nW0T = (u16*)alloc((size_t)128 * 192 * 2);
    u16* nW1T = (u16*)alloc((size_t)128 * 384 * 2);
    u16* eW1T = (u16*)alloc((size_t)128 * 192 * 2);
    u16* eW2T = (u16*)alloc((size_t)128 * 768 * 2);
    u16* fnWT = (u16*)alloc((size_t)64 * 128 * 2);
    u16* feWT = (u16*)alloc((size_t)64 * 128 * 2);
    float* nb0s = (float*)alloc(128 * 4);
    float* nb1s = (float*)alloc(128 * 4);

    // ---- prep (includes zeroing) ----
    SegPack P; int c = 0;
    auto segz = [&](u32* d, int nwords) { P.s[c++] = Seg{nullptr, nullptr, d, nullptr, nwords, 0, 0, 0, 3}; };
    auto segc = [&](const float* s, u16* d, int n, int w_, int ld_) {
        P.s[c++] = Seg{s, d, nullptr, nullptr, n, w_, ld_, 0, 0};
    };
    auto segt = [&](const float* s, u16* d, int Kp, int N, int ldT, int kofs) {
        P.s[c++] = Seg{s, d, nullptr, nullptr, N * Kp, Kp, ldT, kofs, 2};
    };
    segz((u32*)d_ws, (int)(zbytes / 4));
    segc(x,  Zb1n,      262144, 64, 192);
    segc(ex, Zb1e,      262144, 32, 192);
    segc(ex, Zb1e + 96, 262144, 32, 192);
    segt(nW0,  nW0T, 192, 128, 192, 0);
    segt(nW1,  nW1T, 384, 128, 384, 0);
    segt(eWl0, eW1T,  96, 128, 192, 0);
    segt(eWu0, eW1T,  96, 128, 192, 96);
    segt(eWl1, eW2T, 384, 128, 768, 0);
    segt(eWu1, eW2T, 384, 128, 768, 384);
    segt(fnW,  fnWT, 128,  64, 128, 0);
    segt(feW,  feWT, 128,  64, 128, 0);
    P.s[c++] = Seg{nb0, nullptr, nullptr, nb0s, 128, 0, 0, 0, 1};
    P.s[c++] = Seg{nb1, nullptr, nullptr, nb1s, 128, 0, 0, 0, 1};
    P.cnt = c;
    prep_kernel<<<dim3(1024), dim3(256), 0, stream>>>(P);

    // ---- dedup + CSR build ----
    int totE = NE + 2 * NLG;
    insert_kernel<<<dim3((totE + 255) / 256), dim3(256), 0, stream>>>(
        nei, keysA, eil, keysL, valsL, eiu, keysU, valsU);
    int totH = HCA + 2 * HCL;
    hist_kernel<<<dim3(totH / 256), dim3(256), 0, stream>>>(
        keysA, cntA, keysL, cntL, keysU, cntU);
    scan3<<<dim3(3), dim3(256), 0, stream>>>(cntA, ptrA, cntL, ptrL, cntU, ptrU);
    FillArgs fa{keysA, ptrA, fillA, colA,
                keysL, valsL, eal, ptrL, fillL, colL, wL,
                keysU, valsU, eau, ptrU, fillU, colU, wU};
    fill_kernel<<<dim3(totH / 256), dim3(256), 0, stream>>>(fa);

    // ---- helpers ----
    auto gseg = [&](const u32* ptr, const u32* col, const float* wgt,
                    const u16* src, u16* dst, int rows, int gshift, int ld) {
        return GSeg{ptr, col, wgt, src, dst, rows << gshift, gshift, (1 << gshift) - 1, ld};
    };
    auto spmm = [&](GSeg a, GSeg b, GSeg cc) {
        int n = a.n + b.n + cc.n;
        spmm_gather<<<dim3((n + 255) / 256), dim3(256), 0, stream>>>(a, b, cc);
    };
    auto gemm2 = [&](GemmArgs g0, GemmArgs g1, int ncols) {
        mfma_gemm2<<<dim3(g0.mblocks + g1.mblocks, ncols / 64), dim3(64), 0, stream>>>(g0, g1);
    };

    // ---- layer 1 hops (col-groups of 8: node 64c->shift3, edge 32c->shift2) ----
    spmm(gseg(ptrA, colA, nullptr, Zb1n,      Zb1n + 64,  NN, 3, 192),
         gseg(ptrL, colL, wL,      Zb1e,      Zb1e + 32,  NE, 2, 192),
         gseg(ptrU, colU, wU,      Zb1e + 96, Zb1e + 128, NE, 2, 192));
    spmm(gseg(ptrA, colA, nullptr, Zb1n + 64,  Zb1n + 128, NN, 3, 192),
         gseg(ptrL, colL, wL,      Zb1e + 32,  Zb1e + 64,  NE, 2, 192),
         gseg(ptrU, colU, wU,      Zb1e + 128, Zb1e + 160, NE, 2, 192));

    // ---- layer 1 GEMMs ----
    gemm2(GemmArgs{Zb1n, 192, nW0T, 192, nb0s, Zb2n, nullptr, nullptr, 384, 1, 256},
          GemmArgs{Zb1e, 192, eW1T, 192, eb0,  Zb2e, Zb2e + 384, nullptr, 768, 1, 512}, 128);

    // ---- layer 2 hops (128 cols -> shift 4) ----
    spmm(gseg(ptrA, colA, nullptr, Zb2n,       Zb2n + 128, NN, 4, 384),
         gseg(ptrL, colL, wL,      Zb2e,       Zb2e + 128, NE, 4, 768),
         gseg(ptrU, colU, wU,      Zb2e + 384, Zb2e + 512, NE, 4, 768));
    spmm(gseg(ptrA, colA, nullptr, Zb2n + 128, Zb2n + 256, NN, 4, 384),
         gseg(ptrL, colL, wL,      Zb2e + 128, Zb2e + 256, NE, 4, 768),
         gseg(ptrU, colU, wU,      Zb2e + 512, Zb2e + 640, NE, 4, 768));

    // ---- layer 2 GEMMs ----
    gemm2(GemmArgs{Zb2n, 384, nW1T, 384, nb1s, h2b, nullptr, nullptr, 128, 1, 256},
          GemmArgs{Zb2e, 768, eW2T, 768, eb1,  e2b, nullptr, nullptr, 128, 1, 512}, 128);

    // ---- heads -> fp32 d_out ----
    float* outf = (float*)d_out;
    gemm2(GemmArgs{h2b, 128, fnWT, 128, fnb, nullptr, nullptr, outf,          64, 0, 256},
          GemmArgs{e2b, 128, feWT, 128, feb, nullptr, nullptr, outf + 262144, 64, 0, 512}, 64);
}